// Round 1
// baseline (436.024 us; speedup 1.0000x reference)
//
#include <hip/hip_runtime.h>
#include <math.h>

#define B_ 2
#define T_ 50
#define P_ 5111
#define U_ 64

// ---------------------------------------------------------------------------
// ZX[b,t,k] = sum_d xt[b,t,d] * Wk[d,k], where
// xt[b,t,d] = X[tgt[b,t], d&127] * emb2[cor[b,t], d]
// One block per (b,t) pair (100 blocks), 256 threads = one k each.
// ---------------------------------------------------------------------------
__global__ __launch_bounds__(256) void zx_kernel(
    const int* __restrict__ tgt, const int* __restrict__ cor,
    const float* __restrict__ X, const float* __restrict__ emb2,
    const float* __restrict__ Wk, float* __restrict__ ZX) {
  const int bt = blockIdx.x;   // 0..99
  const int k  = threadIdx.x;  // 0..255
  __shared__ float xe[256];
  const int t_ = tgt[bt], c_ = cor[bt];
  xe[k] = X[t_ * 128 + (k & 127)] * emb2[c_ * 256 + k];
  __syncthreads();
  float z = 0.f;
#pragma unroll 8
  for (int d = 0; d < 256; ++d)
    z = fmaf(xe[d], Wk[d * 256 + k], z);
  ZX[bt * 256 + k] = z;
}

// ---------------------------------------------------------------------------
// XWT[j, p] = b1[j] + sum_{u<128} X[p,u] * W1[64+u, j]   (transposed store so
// the main kernel's per-j load is coalesced across p). Block per p, 64 thr.
// ---------------------------------------------------------------------------
__global__ __launch_bounds__(64) void xwt_kernel(
    const float* __restrict__ X, const float* __restrict__ W1,
    const float* __restrict__ b1, float* __restrict__ XWT) {
  const int p = blockIdx.x;
  const int k = threadIdx.x;  // 0..63
  __shared__ float xrow[128];
  xrow[k]      = X[p * 128 + k];
  xrow[64 + k] = X[p * 128 + 64 + k];
  __syncthreads();
  if (k < 50) {
    float acc = b1[k];
#pragma unroll 16
    for (int u = 0; u < 128; ++u)
      acc = fmaf(xrow[u], W1[(64 + u) * 50 + k], acc);
    XWT[k * P_ + p] = acc;
  }
}

// ---------------------------------------------------------------------------
// Sequential LSTM over T=50 with precomputed input matvec ZX. Block per b,
// 256 threads (one z-column each). Wr column kept in registers.
// Also fuses G[b,t,j] = sum_u ht[b,t,u] * W1[u,j]  (j<50).
// Keras gate order i,f,g,o; unit forget bias already inside bl.
// ---------------------------------------------------------------------------
__global__ __launch_bounds__(256) void lstm_kernel(
    const float* __restrict__ ZX, const float* __restrict__ Wr,
    const float* __restrict__ bl, const float* __restrict__ W1,
    float* __restrict__ G) {
  const int b = blockIdx.x;   // 0..1
  const int k = threadIdx.x;  // 0..255
  __shared__ float h_s[64];
  __shared__ float z_s[256];
  float wr[64];
#pragma unroll
  for (int u = 0; u < 64; ++u) wr[u] = Wr[u * 256 + k];
  const float blk = bl[k];
  if (k < 64) h_s[k] = 0.f;
  float c = 0.f;
  __syncthreads();
  for (int t = 0; t < T_; ++t) {
    float z = ZX[(b * T_ + t) * 256 + k] + blk;
#pragma unroll
    for (int u = 0; u < 64; ++u) z = fmaf(h_s[u], wr[u], z);
    z_s[k] = z;
    __syncthreads();
    if (k < 64) {
      const float zi = z_s[k], zf = z_s[64 + k], zg = z_s[128 + k], zo = z_s[192 + k];
      const float ig = 1.f / (1.f + expf(-zi));
      const float fg = 1.f / (1.f + expf(-zf));
      const float gg = tanhf(zg);
      const float og = 1.f / (1.f + expf(-zo));
      c = fg * c + ig * gg;
      h_s[k] = og * tanhf(c);
    }
    __syncthreads();
    if (k < 50) {
      float gv = 0.f;
#pragma unroll
      for (int u = 0; u < 64; ++u) gv = fmaf(h_s[u], W1[u * 50 + k], gv);
      G[(b * T_ + t) * 50 + k] = gv;
    }
    // No extra sync needed: h_s is next written only after the next
    // iteration's first __syncthreads(); z_s rewrite is fenced by sync2.
  }
}

// ---------------------------------------------------------------------------
// Main fused kernel: thread per (b,p). Suffix-sum S[j] over s=49..0:
//   S starts at XW[p,:]; S += a[b,s,p]*G[b,s,:]; out = relu(S)·W2 + b2.
// a[b,s,p] = cos_X[tgt[b,s], p]  -> coalesced across p.
// ---------------------------------------------------------------------------
__global__ __launch_bounds__(256) void out_kernel(
    const int* __restrict__ tgt, const float* __restrict__ cosX,
    const float* __restrict__ G, const float* __restrict__ XWT,
    const float* __restrict__ W2, const float* __restrict__ b2,
    float* __restrict__ out) {
  const int b   = blockIdx.y;
  const int tid = threadIdx.x;
  const int p   = blockIdx.x * 256 + tid;
  __shared__ float G_s[T_ * 50];
  __shared__ float W2_s[50];
  __shared__ int   tgt_s[T_];
  for (int i = tid; i < T_ * 50; i += 256) G_s[i] = G[b * T_ * 50 + i];
  if (tid < 50) {
    W2_s[tid]  = W2[tid];
    tgt_s[tid] = tgt[b * T_ + tid];
  }
  __syncthreads();
  if (p >= P_) return;
  float S[50];
#pragma unroll
  for (int j = 0; j < 50; ++j) S[j] = XWT[j * P_ + p];
  const float b2v = b2[0];
  for (int s = T_ - 1; s >= 0; --s) {
    const float av = cosX[tgt_s[s] * P_ + p];
    const float* Gs = &G_s[s * 50];
    float acc = b2v;
#pragma unroll
    for (int j = 0; j < 50; ++j) {
      S[j] = fmaf(av, Gs[j], S[j]);
      acc  = fmaf(fmaxf(S[j], 0.f), W2_s[j], acc);
    }
    out[(b * T_ + s) * P_ + p] = acc;
  }
}

extern "C" void kernel_launch(void* const* d_in, const int* in_sizes, int n_in,
                              void* d_out, int out_size, void* d_ws, size_t ws_size,
                              hipStream_t stream) {
  const int*   tgt  = (const int*)d_in[0];
  const int*   cor  = (const int*)d_in[1];
  // d_in[2] = num_pro (scalar), shapes are compile-time constants here
  const float* X    = (const float*)d_in[3];
  const float* cosX = (const float*)d_in[4];
  // d_in[5] = trimatrix (folded into the suffix-sum algebra)
  const float* emb2 = (const float*)d_in[6];
  const float* Wk   = (const float*)d_in[7];
  const float* Wr   = (const float*)d_in[8];
  const float* bl   = (const float*)d_in[9];
  const float* W1   = (const float*)d_in[10];
  const float* b1   = (const float*)d_in[11];
  const float* W2   = (const float*)d_in[12];
  const float* b2   = (const float*)d_in[13];
  float* out = (float*)d_out;

  float* ws  = (float*)d_ws;
  float* ZX  = ws;           // 100*256 = 25600 floats
  float* G   = ws + 25600;   // 100*50  =  5000 floats
  float* XWT = ws + 30600;   // 50*5111 = 255550 floats  (~1.14 MB total)

  zx_kernel<<<dim3(B_ * T_), dim3(256), 0, stream>>>(tgt, cor, X, emb2, Wk, ZX);
  xwt_kernel<<<dim3(P_), dim3(64), 0, stream>>>(X, W1, b1, XWT);
  lstm_kernel<<<dim3(B_), dim3(256), 0, stream>>>(ZX, Wr, bl, W1, G);
  out_kernel<<<dim3((P_ + 255) / 256, B_), dim3(256), 0, stream>>>(
      tgt, cosX, G, XWT, W2, b2, out);
}

// Round 2
// 274.636 us; speedup vs baseline: 1.5876x; 1.5876x over previous
//
#include <hip/hip_runtime.h>
#include <math.h>

#define B_ 2
#define T_ 50
#define P_ 5111
#define U_ 64

// ---------------------------------------------------------------------------
// Fused preprocessing kernel.
// Blocks 0..99 (role Z): ZX[b,t,k] = sum_d xt[b,t,d] * Wk[d,k],
//   xt[b,t,d] = X[tgt[b,t], d&127] * emb2[cor[b,t], d].  256 thr, one k each.
// Blocks 100.. (role XW): XWT[j,p] = b1[j] + sum_{u<128} X[p,u]*W1[64+u,j].
//   4 p-values per block (tid>>6 selects p, tid&63 is j with j<50 guard).
// Role is block-uniform, so the divergent __syncthreads are legal.
// ---------------------------------------------------------------------------
__global__ __launch_bounds__(256) void pre_kernel(
    const int* __restrict__ tgt, const int* __restrict__ cor,
    const float* __restrict__ X, const float* __restrict__ emb2,
    const float* __restrict__ Wk, const float* __restrict__ W1,
    const float* __restrict__ b1,
    float* __restrict__ ZX, float* __restrict__ XWT) {
  __shared__ float xe[256];        // role Z
  __shared__ float xrow[4][128];   // role XW
  const int blk = blockIdx.x;
  const int tid = threadIdx.x;
  if (blk < B_ * T_) {
    const int t_ = tgt[blk], c_ = cor[blk];
    xe[tid] = X[t_ * 128 + (tid & 127)] * emb2[c_ * 256 + tid];
    __syncthreads();
    float z = 0.f;
#pragma unroll 8
    for (int d = 0; d < 256; ++d)
      z = fmaf(xe[d], Wk[d * 256 + tid], z);
    ZX[blk * 256 + tid] = z;
  } else {
    const int sub = tid >> 6, lane = tid & 63;
    const int p = (blk - B_ * T_) * 4 + sub;
    if (p < P_) {
      xrow[sub][lane]      = X[p * 128 + lane];
      xrow[sub][64 + lane] = X[p * 128 + 64 + lane];
    }
    __syncthreads();
    if (p < P_ && lane < 50) {
      float acc = b1[lane];
#pragma unroll 16
      for (int u = 0; u < 128; ++u)
        acc = fmaf(xrow[sub][u], W1[(64 + u) * 50 + lane], acc);
      XWT[lane * P_ + p] = acc;
    }
  }
}

// ---------------------------------------------------------------------------
// Sequential LSTM, latency-optimized. One block per batch, 320 threads:
//   k <  256 : z-column k  (Wr column + all 50 ZX values + bias in registers)
//   256<=k<306: G-column j=k-256 (W1 column in registers); computes
//              G(t-1)[j] = sum_u h(t-1)[u]*W1[u,j] concurrently with the
//              z matvec of step t (both read the same h(t-1) broadcast).
//   k >= 306 : idle (barrier participants only)
// Per step: ONE h-broadcast phase (16x float4 LDS reads, 4 indep FMA chains),
// 2 barriers, fast __expf/__fdividef gates on threads k<64.
// No global loads inside the loop at all; only the G store (fire-and-forget).
// ---------------------------------------------------------------------------
__global__ __launch_bounds__(320) void lstm_kernel(
    const float* __restrict__ ZX, const float* __restrict__ Wr,
    const float* __restrict__ bl, const float* __restrict__ W1,
    float* __restrict__ G) {
  const int b = blockIdx.x;
  const int k = threadIdx.x;
  __shared__ __align__(16) float h_s[64];
  __shared__ float z_s[256];
  const bool is_z = (k < 256);
  const bool is_g = (k >= 256) && (k < 306);
  float w[64];
  float zx[T_];
  float blk = 0.f;
  if (is_z) {
#pragma unroll
    for (int u = 0; u < 64; ++u) w[u] = Wr[u * 256 + k];
#pragma unroll
    for (int t = 0; t < T_; ++t) zx[t] = ZX[(b * T_ + t) * 256 + k];
    blk = bl[k];
  } else if (is_g) {
    const int j = k - 256;
#pragma unroll
    for (int u = 0; u < 64; ++u) w[u] = W1[u * 50 + j];
  }
  float c = 0.f;
  if (k < 64) h_s[k] = 0.f;
  __syncthreads();

  for (int t = 0; t < T_; ++t) {
    // --- matvec against h(t-1) (all compute threads, one broadcast phase) ---
    float a0 = 0.f, a1 = 0.f, a2 = 0.f, a3 = 0.f;
    if (is_z || is_g) {
      const float4* h4 = (const float4*)h_s;
#pragma unroll
      for (int q = 0; q < 16; ++q) {
        const float4 hq = h4[q];
        a0 = fmaf(hq.x, w[4 * q + 0], a0);
        a1 = fmaf(hq.y, w[4 * q + 1], a1);
        a2 = fmaf(hq.z, w[4 * q + 2], a2);
        a3 = fmaf(hq.w, w[4 * q + 3], a3);
      }
    }
    const float mv = (a0 + a1) + (a2 + a3);
    if (is_z) z_s[k] = mv + zx[t] + blk;
    if (is_g && t > 0) G[(b * T_ + (t - 1)) * 50 + (k - 256)] = mv;
    __syncthreads();
    // --- gates (keras order i,f,g,o) on threads k<64 ---
    if (k < 64) {
      const float zi = z_s[k], zf = z_s[64 + k], zg = z_s[128 + k], zo = z_s[192 + k];
      const float ig = __fdividef(1.f, 1.f + __expf(-zi));
      const float fg = __fdividef(1.f, 1.f + __expf(-zf));
      const float gg = 1.f - __fdividef(2.f, 1.f + __expf(2.f * zg));
      const float og = __fdividef(1.f, 1.f + __expf(-zo));
      c = fg * c + ig * gg;
      const float th = 1.f - __fdividef(2.f, 1.f + __expf(2.f * c));
      h_s[k] = og * th;
    }
    __syncthreads();
  }
  // --- final G(49) from h(49) ---
  if (is_g) {
    float a0 = 0.f, a1 = 0.f, a2 = 0.f, a3 = 0.f;
    const float4* h4 = (const float4*)h_s;
#pragma unroll
    for (int q = 0; q < 16; ++q) {
      const float4 hq = h4[q];
      a0 = fmaf(hq.x, w[4 * q + 0], a0);
      a1 = fmaf(hq.y, w[4 * q + 1], a1);
      a2 = fmaf(hq.z, w[4 * q + 2], a2);
      a3 = fmaf(hq.w, w[4 * q + 3], a3);
    }
    G[(b * T_ + (T_ - 1)) * 50 + (k - 256)] = (a0 + a1) + (a2 + a3);
  }
}

// ---------------------------------------------------------------------------
// Main fused kernel: thread per (b,p). Suffix-sum S[j] over s=49..0 with the
// next cosX row PREFETCHED one step ahead (the only dependent global load).
// ---------------------------------------------------------------------------
__global__ __launch_bounds__(256) void out_kernel(
    const int* __restrict__ tgt, const float* __restrict__ cosX,
    const float* __restrict__ G, const float* __restrict__ XWT,
    const float* __restrict__ W2, const float* __restrict__ b2,
    float* __restrict__ out) {
  const int b   = blockIdx.y;
  const int tid = threadIdx.x;
  const int p   = blockIdx.x * 256 + tid;
  __shared__ float G_s[T_ * 50];
  __shared__ float W2_s[50];
  __shared__ int   tgt_s[T_];
  for (int i = tid; i < T_ * 50; i += 256) G_s[i] = G[b * T_ * 50 + i];
  if (tid < 50) {
    W2_s[tid]  = W2[tid];
    tgt_s[tid] = tgt[b * T_ + tid];
  }
  __syncthreads();
  if (p >= P_) return;
  float S[50];
#pragma unroll
  for (int j = 0; j < 50; ++j) S[j] = XWT[j * P_ + p];
  const float b2v = b2[0];
  float av = cosX[tgt_s[T_ - 1] * P_ + p];
  for (int s = T_ - 1; s >= 0; --s) {
    const float av_next = (s > 0) ? cosX[tgt_s[s - 1] * P_ + p] : 0.f;
    const float* Gs = &G_s[s * 50];
    float acc = b2v;
#pragma unroll
    for (int j = 0; j < 50; ++j) {
      S[j] = fmaf(av, Gs[j], S[j]);
      acc  = fmaf(fmaxf(S[j], 0.f), W2_s[j], acc);
    }
    out[(b * T_ + s) * P_ + p] = acc;
    av = av_next;
  }
}

extern "C" void kernel_launch(void* const* d_in, const int* in_sizes, int n_in,
                              void* d_out, int out_size, void* d_ws, size_t ws_size,
                              hipStream_t stream) {
  const int*   tgt  = (const int*)d_in[0];
  const int*   cor  = (const int*)d_in[1];
  const float* X    = (const float*)d_in[3];
  const float* cosX = (const float*)d_in[4];
  const float* emb2 = (const float*)d_in[6];
  const float* Wk   = (const float*)d_in[7];
  const float* Wr   = (const float*)d_in[8];
  const float* bl   = (const float*)d_in[9];
  const float* W1   = (const float*)d_in[10];
  const float* b1   = (const float*)d_in[11];
  const float* W2   = (const float*)d_in[12];
  const float* b2   = (const float*)d_in[13];
  float* out = (float*)d_out;

  float* ws  = (float*)d_ws;
  float* ZX  = ws;           // 100*256 = 25600 floats
  float* G   = ws + 25600;   // 100*50  =  5000 floats
  float* XWT = ws + 30600;   // 50*5111 = 255550 floats

  const int xw_blocks = (P_ + 3) / 4;           // 1278
  pre_kernel<<<dim3(B_ * T_ + xw_blocks), dim3(256), 0, stream>>>(
      tgt, cor, X, emb2, Wk, W1, b1, ZX, XWT);
  lstm_kernel<<<dim3(B_), dim3(320), 0, stream>>>(ZX, Wr, bl, W1, G);
  out_kernel<<<dim3((P_ + 255) / 256, B_), dim3(256), 0, stream>>>(
      tgt, cosX, G, XWT, W2, b2, out);
}

// Round 3
// 251.254 us; speedup vs baseline: 1.7354x; 1.0931x over previous
//
#include <hip/hip_runtime.h>
#include <math.h>

#define B_ 2
#define T_ 50
#define P_ 5111
#define U_ 64

// ---------------------------------------------------------------------------
// Fused preprocessing kernel (unchanged from round 2).
// Blocks 0..99 (role Z): ZX[b,t,k] = sum_d xt[b,t,d] * Wk[d,k],
//   xt[b,t,d] = X[tgt[b,t], d&127] * emb2[cor[b,t], d].
// Blocks 100.. (role XW): XWT[j,p] = b1[j] + sum_{u<128} X[p,u]*W1[64+u,j].
// ---------------------------------------------------------------------------
__global__ __launch_bounds__(256) void pre_kernel(
    const int* __restrict__ tgt, const int* __restrict__ cor,
    const float* __restrict__ X, const float* __restrict__ emb2,
    const float* __restrict__ Wk, const float* __restrict__ W1,
    const float* __restrict__ b1,
    float* __restrict__ ZX, float* __restrict__ XWT) {
  __shared__ float xe[256];
  __shared__ float xrow[4][128];
  const int blk = blockIdx.x;
  const int tid = threadIdx.x;
  if (blk < B_ * T_) {
    const int t_ = tgt[blk], c_ = cor[blk];
    xe[tid] = X[t_ * 128 + (tid & 127)] * emb2[c_ * 256 + tid];
    __syncthreads();
    float z = 0.f;
#pragma unroll 8
    for (int d = 0; d < 256; ++d)
      z = fmaf(xe[d], Wk[d * 256 + tid], z);
    ZX[blk * 256 + tid] = z;
  } else {
    const int sub = tid >> 6, lane = tid & 63;
    const int p = (blk - B_ * T_) * 4 + sub;
    if (p < P_) {
      xrow[sub][lane]      = X[p * 128 + lane];
      xrow[sub][64 + lane] = X[p * 128 + 64 + lane];
    }
    __syncthreads();
    if (p < P_ && lane < 50) {
      float acc = b1[lane];
#pragma unroll 16
      for (int u = 0; u < 128; ++u)
        acc = fmaf(xrow[sub][u], W1[(64 + u) * 50 + lane], acc);
      XWT[lane * P_ + p] = acc;
    }
  }
}

// ---------------------------------------------------------------------------
// Sequential LSTM, latency-optimized v3. One block per batch, 320 threads.
//   k < 256 : z-thread for column col = (k&3)*64 + (k>>2)  i.e. gate g=k&3,
//             unit u=k>>2. The 4 gates of a unit are in ADJACENT LANES, so
//             gate combination is 3x __shfl_xor — no z_s LDS, no 2nd barrier.
//   256<=k<306 : G-thread j=k-256; matvec of h(t-1) against W1 column runs
//             concurrently with the z matvec; result kept in LDS (G_s),
//             dumped to global once at the end (no vmcnt drain per barrier).
// h_s double-buffered -> single __syncthreads per step.
// ZX: rolling one-step register prefetch (NO dynamically-indexed private
// array -> no scratch, which was round 2's hidden critical-path load).
// ---------------------------------------------------------------------------
__global__ __launch_bounds__(320) void lstm_kernel(
    const float* __restrict__ ZX, const float* __restrict__ Wr,
    const float* __restrict__ bl, const float* __restrict__ W1,
    float* __restrict__ G) {
  const int b = blockIdx.x;
  const int k = threadIdx.x;
  __shared__ __align__(16) float h_s[2][64];
  __shared__ float G_s[T_][50];
  const bool is_z = (k < 256);
  const bool is_g = (k >= 256) && (k < 306);
  const int g   = k & 3;
  const int u   = k >> 2;
  const int col = g * 64 + u;   // original z column (i|f|g|o blocks of 64)
  const int j   = k - 256;

  float w[64];
  float blv = 0.f, znext = 0.f;
  if (is_z) {
#pragma unroll
    for (int u2 = 0; u2 < 64; ++u2) w[u2] = Wr[u2 * 256 + col];
    blv = bl[col];
    znext = ZX[(b * T_) * 256 + col];
  } else if (is_g) {
#pragma unroll
    for (int u2 = 0; u2 < 64; ++u2) w[u2] = W1[u2 * 50 + j];
  }
  if (k < 64) h_s[0][k] = 0.f;
  float c = 0.f;
  __syncthreads();

  for (int t = 0; t < T_; ++t) {
    const int rb = t & 1, wb = rb ^ 1;
    const float zcur = znext;
    if (is_z && t + 1 < T_) znext = ZX[(b * T_ + t + 1) * 256 + col];
    float a0 = 0.f, a1 = 0.f, a2 = 0.f, a3 = 0.f;
    if (is_z || is_g) {
      const float4* h4 = (const float4*)h_s[rb];
#pragma unroll
      for (int q = 0; q < 16; ++q) {
        const float4 hq = h4[q];
        a0 = fmaf(hq.x, w[4 * q + 0], a0);
        a1 = fmaf(hq.y, w[4 * q + 1], a1);
        a2 = fmaf(hq.z, w[4 * q + 2], a2);
        a3 = fmaf(hq.w, w[4 * q + 3], a3);
      }
    }
    const float mv = (a0 + a1) + (a2 + a3);
    if (is_z) {
      const float z = mv + zcur + blv;
      // gate nonlinearity: g==2 -> tanh, else sigmoid
      const bool isg2 = (g == 2);
      const float arg = isg2 ? (2.f * z) : (-z);
      const float e   = __expf(arg);
      const float v   = __fdividef(1.f, 1.f + e);
      const float res = isg2 ? fmaf(-2.f, v, 1.f) : v;
      // exchange gates within the 4-lane unit group
      const float v1 = __shfl_xor(res, 1);
      const float v2 = __shfl_xor(res, 2);
      const float v3 = __shfl_xor(res, 3);
      // gate m's value lives in v_{m^g} (v0 == res)
      const float ig = (g == 0) ? res : (g == 1) ? v1 : (g == 2) ? v2 : v3;
      const float fg = (g == 1) ? res : (g == 0) ? v1 : (g == 3) ? v2 : v3;
      const float gg = (g == 2) ? res : (g == 3) ? v1 : (g == 0) ? v2 : v3;
      const float og = (g == 3) ? res : (g == 2) ? v1 : (g == 1) ? v2 : v3;
      c = fmaf(fg, c, ig * gg);   // identical in all 4 lanes of the unit
      const float e2 = __expf(2.f * c);
      const float th = fmaf(-2.f, __fdividef(1.f, 1.f + e2), 1.f);
      if (g == 0) h_s[wb][u] = og * th;
    } else if (is_g && t > 0) {
      G_s[t - 1][j] = mv;         // G(t-1) = h(t-1)·W1
    }
    __syncthreads();              // single barrier: fences h_s[wb] for next read
  }
  // final G(T-1) from h(T-1), which sits in buffer (T_ & 1)
  if (is_g) {
    const float4* h4 = (const float4*)h_s[T_ & 1];
    float a0 = 0.f, a1 = 0.f, a2 = 0.f, a3 = 0.f;
#pragma unroll
    for (int q = 0; q < 16; ++q) {
      const float4 hq = h4[q];
      a0 = fmaf(hq.x, w[4 * q + 0], a0);
      a1 = fmaf(hq.y, w[4 * q + 1], a1);
      a2 = fmaf(hq.z, w[4 * q + 2], a2);
      a3 = fmaf(hq.w, w[4 * q + 3], a3);
    }
    G_s[T_ - 1][j] = (a0 + a1) + (a2 + a3);
  }
  __syncthreads();
  // coalesced dump of G_s -> G[b, :, :]
  for (int i = k; i < T_ * 50; i += 320)
    G[b * T_ * 50 + i] = (&G_s[0][0])[i];
}

// ---------------------------------------------------------------------------
// Main fused kernel (unchanged from round 2): thread per (b,p), suffix-sum
// S[j] over s=49..0 with next cosX row prefetched one step ahead.
// ---------------------------------------------------------------------------
__global__ __launch_bounds__(256) void out_kernel(
    const int* __restrict__ tgt, const float* __restrict__ cosX,
    const float* __restrict__ G, const float* __restrict__ XWT,
    const float* __restrict__ W2, const float* __restrict__ b2,
    float* __restrict__ out) {
  const int b   = blockIdx.y;
  const int tid = threadIdx.x;
  const int p   = blockIdx.x * 256 + tid;
  __shared__ float G_s[T_ * 50];
  __shared__ float W2_s[50];
  __shared__ int   tgt_s[T_];
  for (int i = tid; i < T_ * 50; i += 256) G_s[i] = G[b * T_ * 50 + i];
  if (tid < 50) {
    W2_s[tid]  = W2[tid];
    tgt_s[tid] = tgt[b * T_ + tid];
  }
  __syncthreads();
  if (p >= P_) return;
  float S[50];
#pragma unroll
  for (int j = 0; j < 50; ++j) S[j] = XWT[j * P_ + p];
  const float b2v = b2[0];
  float av = cosX[tgt_s[T_ - 1] * P_ + p];
  for (int s = T_ - 1; s >= 0; --s) {
    const float av_next = (s > 0) ? cosX[tgt_s[s - 1] * P_ + p] : 0.f;
    const float* Gs = &G_s[s * 50];
    float acc = b2v;
#pragma unroll
    for (int j = 0; j < 50; ++j) {
      S[j] = fmaf(av, Gs[j], S[j]);
      acc  = fmaf(fmaxf(S[j], 0.f), W2_s[j], acc);
    }
    out[(b * T_ + s) * P_ + p] = acc;
    av = av_next;
  }
}

extern "C" void kernel_launch(void* const* d_in, const int* in_sizes, int n_in,
                              void* d_out, int out_size, void* d_ws, size_t ws_size,
                              hipStream_t stream) {
  const int*   tgt  = (const int*)d_in[0];
  const int*   cor  = (const int*)d_in[1];
  const float* X    = (const float*)d_in[3];
  const float* cosX = (const float*)d_in[4];
  const float* emb2 = (const float*)d_in[6];
  const float* Wk   = (const float*)d_in[7];
  const float* Wr   = (const float*)d_in[8];
  const float* bl   = (const float*)d_in[9];
  const float* W1   = (const float*)d_in[10];
  const float* b1   = (const float*)d_in[11];
  const float* W2   = (const float*)d_in[12];
  const float* b2   = (const float*)d_in[13];
  float* out = (float*)d_out;

  float* ws  = (float*)d_ws;
  float* ZX  = ws;           // 100*256 = 25600 floats
  float* G   = ws + 25600;   // 100*50  =  5000 floats
  float* XWT = ws + 30600;   // 50*5111 = 255550 floats

  const int xw_blocks = (P_ + 3) / 4;
  pre_kernel<<<dim3(B_ * T_ + xw_blocks), dim3(256), 0, stream>>>(
      tgt, cor, X, emb2, Wk, W1, b1, ZX, XWT);
  lstm_kernel<<<dim3(B_), dim3(320), 0, stream>>>(ZX, Wr, bl, W1, G);
  out_kernel<<<dim3((P_ + 255) / 256, B_), dim3(256), 0, stream>>>(
      tgt, cosX, G, XWT, W2, b2, out);
}

// Round 4
// 250.740 us; speedup vs baseline: 1.7390x; 1.0020x over previous
//
#include <hip/hip_runtime.h>
#include <math.h>

#define B_ 2
#define T_ 50
#define P_ 5111
#define U_ 64

typedef float v2f __attribute__((ext_vector_type(2)));

// quad_perm DPP: dest lane i (within quad) <- src lane sel[i]
// xor1 = [1,0,3,2] = 177, xor2 = [2,3,0,1] = 78, xor3 = [3,2,1,0] = 27
#define QPERM(x, ctrl)                                                        \
  __int_as_float(__builtin_amdgcn_mov_dpp(__float_as_int(x), (ctrl), 0xf, 0xf, true))

// ---------------------------------------------------------------------------
// ZX[b,t,k] = sum_d xt[b,t,d] * Wk[d,k],
//   xt[b,t,d] = X[tgt[b,t], d&127] * emb2[cor[b,t], d].  100 blocks.
// ---------------------------------------------------------------------------
__global__ __launch_bounds__(256) void zx_kernel(
    const int* __restrict__ tgt, const int* __restrict__ cor,
    const float* __restrict__ X, const float* __restrict__ emb2,
    const float* __restrict__ Wk, float* __restrict__ ZX) {
  const int bt = blockIdx.x;
  const int k  = threadIdx.x;
  __shared__ float xe[256];
  const int t_ = tgt[bt], c_ = cor[bt];
  xe[k] = X[t_ * 128 + (k & 127)] * emb2[c_ * 256 + k];
  __syncthreads();
  float z = 0.f;
#pragma unroll 8
  for (int d = 0; d < 256; ++d)
    z = fmaf(xe[d], Wk[d * 256 + k], z);
  ZX[bt * 256 + k] = z;
}

// ---------------------------------------------------------------------------
// Fused LSTM (blocks 0,1) + XWT (blocks 2..) kernel.
//
// LSTM role: 256 threads = 4 waves, thread k -> gate g=k&3, unit u=k>>2,
//   z-column col=g*64+u. Gates of one unit sit in one QUAD -> gate exchange
//   is 3x v_mov_b32_dpp quad_perm (no DS, no extra barrier).
//   h history kept in LDS H_s[t] (read row t, write row t+1, ONE barrier).
//   Matvec: 32x v_pk_fma_f32 (4 chains of 8). ZX: rolling register prefetch.
//   Epilogue (off serial path): G[b,t,:] = H(t)·W1 using W1 staged in LDS.
//
// XWT role: XWT[j,p] = b1[j] + sum_{u<128} X[p,u]*W1[64+u,j], 4 p per block.
// ---------------------------------------------------------------------------
__global__ __launch_bounds__(256) void lstm_xwt_kernel(
    const float* __restrict__ ZX, const float* __restrict__ Wr,
    const float* __restrict__ bl, const float* __restrict__ W1,
    const float* __restrict__ X, const float* __restrict__ b1,
    float* __restrict__ G, float* __restrict__ XWT) {
  const int blk = blockIdx.x;
  const int k   = threadIdx.x;

  if (blk >= B_) {
    // ---------------- XWT role ----------------
    __shared__ float xrow[4][128];
    const int sub = k >> 6, lane = k & 63;
    const int p = (blk - B_) * 4 + sub;
    if (p < P_) {
      xrow[sub][lane]      = X[p * 128 + lane];
      xrow[sub][64 + lane] = X[p * 128 + 64 + lane];
    }
    __syncthreads();
    if (p < P_ && lane < 50) {
      float acc = b1[lane];
#pragma unroll 16
      for (int u = 0; u < 128; ++u)
        acc = fmaf(xrow[sub][u], W1[(64 + u) * 50 + lane], acc);
      XWT[lane * P_ + p] = acc;
    }
    return;
  }

  // ---------------- LSTM role ----------------
  const int b   = blk;
  const int g   = k & 3;
  const int u   = k >> 2;
  const int col = g * 64 + u;
  __shared__ __align__(16) float H_s[T_ + 1][64];   // H_s[t] = h(t-1)
  __shared__ __align__(16) float W1_s[64 * 50];

  v2f w2[32];
#pragma unroll
  for (int i = 0; i < 32; ++i) {
    v2f t; t.x = Wr[(2 * i) * 256 + col]; t.y = Wr[(2 * i + 1) * 256 + col];
    w2[i] = t;
  }
  const float blv = bl[col];
  float znext = ZX[(b * T_) * 256 + col];
  for (int i = k; i < 64 * 50; i += 256) W1_s[i] = W1[i];
  if (k < 64) H_s[0][k] = 0.f;
  float c = 0.f;
  __syncthreads();

  for (int t = 0; t < T_; ++t) {
    const float zcur = znext;
    if (t + 1 < T_) znext = ZX[(b * T_ + t + 1) * 256 + col];
    const float4* h4 = (const float4*)&H_s[t][0];
    v2f a0 = {0.f, 0.f}, a1 = {0.f, 0.f}, a2 = {0.f, 0.f}, a3 = {0.f, 0.f};
#pragma unroll
    for (int q = 0; q < 16; ++q) {
      const float4 hq = h4[q];
      v2f hlo; hlo.x = hq.x; hlo.y = hq.y;
      v2f hhi; hhi.x = hq.z; hhi.y = hq.w;
      if (q & 1) {
        a2 = __builtin_elementwise_fma(hlo, w2[2 * q], a2);
        a3 = __builtin_elementwise_fma(hhi, w2[2 * q + 1], a3);
      } else {
        a0 = __builtin_elementwise_fma(hlo, w2[2 * q], a0);
        a1 = __builtin_elementwise_fma(hhi, w2[2 * q + 1], a1);
      }
    }
    const v2f as = (a0 + a2) + (a1 + a3);
    const float z = as.x + as.y + zcur + blv;
    // gate nonlinearity: g==2 -> tanh, else sigmoid
    const bool isg2 = (g == 2);
    const float arg = isg2 ? (2.f * z) : (-z);
    const float e   = __expf(arg);
    const float v   = __fdividef(1.f, 1.f + e);
    const float res = isg2 ? fmaf(-2.f, v, 1.f) : v;
    // exchange within the quad via DPP (vN = value from lane g^N)
    const float v1 = QPERM(res, 177);
    const float v2 = QPERM(res, 78);
    const float v3 = QPERM(res, 27);
    const float ig = (g == 0) ? res : (g == 1) ? v1 : (g == 2) ? v2 : v3;
    const float fg = (g == 1) ? res : (g == 0) ? v1 : (g == 3) ? v2 : v3;
    const float gg = (g == 2) ? res : (g == 3) ? v1 : (g == 0) ? v2 : v3;
    const float og = (g == 3) ? res : (g == 2) ? v1 : (g == 1) ? v2 : v3;
    c = fmaf(fg, c, ig * gg);
    const float th = fmaf(-2.f, __fdividef(1.f, 1.f + __expf(2.f * c)), 1.f);
    if (g == 0) H_s[t + 1][u] = og * th;
    __syncthreads();
  }

  // Epilogue (not on the serial path): G[b,t,2jp:2jp+2] = H(t)·W1 pairs.
  const v2f* W1_2 = (const v2f*)W1_s;
  v2f*       G_2  = (v2f*)G;  // G rows are 50 floats; all pair indices even
  for (int task = k; task < T_ * 25; task += 256) {
    const int t  = task / 25;
    const int jp = task % 25;
    const float* hrow = &H_s[t + 1][0];
    v2f acc = {0.f, 0.f};
#pragma unroll
    for (int u2 = 0; u2 < 64; ++u2) {
      v2f hb; hb.x = hrow[u2]; hb.y = hrow[u2];
      acc = __builtin_elementwise_fma(hb, W1_2[u2 * 25 + jp], acc);
    }
    G_2[b * (T_ * 25) + task] = acc;
  }
}

// ---------------------------------------------------------------------------
// Main fused kernel: thread per (b,p). Suffix-sum S over s=49..0, packed
// float2 (v_pk_fma_f32 / v_pk_max_f32); next cosX row prefetched one ahead.
// ---------------------------------------------------------------------------
__global__ __launch_bounds__(256) void out_kernel(
    const int* __restrict__ tgt, const float* __restrict__ cosX,
    const float* __restrict__ G, const float* __restrict__ XWT,
    const float* __restrict__ W2, const float* __restrict__ b2,
    float* __restrict__ out) {
  const int b   = blockIdx.y;
  const int tid = threadIdx.x;
  const int p   = blockIdx.x * 256 + tid;
  __shared__ __align__(16) float G_s[T_ * 50];
  __shared__ __align__(16) float W2_s[50];
  __shared__ int tgt_s[T_];
  for (int i = tid; i < T_ * 50; i += 256) G_s[i] = G[b * T_ * 50 + i];
  if (tid < 50) {
    W2_s[tid]  = W2[tid];
    tgt_s[tid] = tgt[b * T_ + tid];
  }
  __syncthreads();
  if (p >= P_) return;
  v2f S2[25];
#pragma unroll
  for (int jj = 0; jj < 25; ++jj) {
    v2f t; t.x = XWT[(2 * jj) * P_ + p]; t.y = XWT[(2 * jj + 1) * P_ + p];
    S2[jj] = t;
  }
  const v2f* W2_2 = (const v2f*)W2_s;
  const float b2v = b2[0];
  const v2f zero2 = {0.f, 0.f};
  float av = cosX[tgt_s[T_ - 1] * P_ + p];
  for (int s = T_ - 1; s >= 0; --s) {
    const float av_next = (s > 0) ? cosX[tgt_s[s - 1] * P_ + p] : 0.f;
    const v2f* G2 = (const v2f*)&G_s[s * 50];
    v2f av2; av2.x = av; av2.y = av;
    v2f acc2; acc2.x = b2v; acc2.y = 0.f;
#pragma unroll
    for (int jj = 0; jj < 25; ++jj) {
      S2[jj] = __builtin_elementwise_fma(av2, G2[jj], S2[jj]);
      const v2f r = __builtin_elementwise_max(S2[jj], zero2);
      acc2 = __builtin_elementwise_fma(r, W2_2[jj], acc2);
    }
    out[(b * T_ + s) * P_ + p] = acc2.x + acc2.y;
    av = av_next;
  }
}

extern "C" void kernel_launch(void* const* d_in, const int* in_sizes, int n_in,
                              void* d_out, int out_size, void* d_ws, size_t ws_size,
                              hipStream_t stream) {
  const int*   tgt  = (const int*)d_in[0];
  const int*   cor  = (const int*)d_in[1];
  const float* X    = (const float*)d_in[3];
  const float* cosX = (const float*)d_in[4];
  const float* emb2 = (const float*)d_in[6];
  const float* Wk   = (const float*)d_in[7];
  const float* Wr   = (const float*)d_in[8];
  const float* bl   = (const float*)d_in[9];
  const float* W1   = (const float*)d_in[10];
  const float* b1   = (const float*)d_in[11];
  const float* W2   = (const float*)d_in[12];
  const float* b2   = (const float*)d_in[13];
  float* out = (float*)d_out;

  float* ws  = (float*)d_ws;
  float* ZX  = ws;           // 100*256 = 25600 floats
  float* G   = ws + 25600;   // 100*50  =  5000 floats
  float* XWT = ws + 30600;   // 50*5111 = 255550 floats

  const int xw_blocks = (P_ + 3) / 4;  // 1278
  zx_kernel<<<dim3(B_ * T_), dim3(256), 0, stream>>>(tgt, cor, X, emb2, Wk, ZX);
  lstm_xwt_kernel<<<dim3(B_ + xw_blocks), dim3(256), 0, stream>>>(
      ZX, Wr, bl, W1, X, b1, G, XWT);
  out_kernel<<<dim3((P_ + 255) / 256, B_), dim3(256), 0, stream>>>(
      tgt, cosX, G, XWT, W2, b2, out);
}

// Round 5
// 249.098 us; speedup vs baseline: 1.7504x; 1.0066x over previous
//
#include <hip/hip_runtime.h>
#include <math.h>

#define B_ 2
#define T_ 50
#define P_ 5111
#define U_ 64

typedef float v2f __attribute__((ext_vector_type(2)));

// quad_perm DPP: dest lane i (within quad) <- src lane sel[i]
#define QPERM(x, ctrl)                                                        \
  __int_as_float(__builtin_amdgcn_mov_dpp(__float_as_int(x), (ctrl), 0xf, 0xf, true))

// ---------------------------------------------------------------------------
// ZX[b,t,k] = sum_d xt[b,t,d] * Wk[d,k],
//   xt[b,t,d] = X[tgt[b,t], d&127] * emb2[cor[b,t], d].  100 blocks.
// ---------------------------------------------------------------------------
__global__ __launch_bounds__(256) void zx_kernel(
    const int* __restrict__ tgt, const int* __restrict__ cor,
    const float* __restrict__ X, const float* __restrict__ emb2,
    const float* __restrict__ Wk, float* __restrict__ ZX) {
  const int bt = blockIdx.x;
  const int k  = threadIdx.x;
  __shared__ float xe[256];
  const int t_ = tgt[bt], c_ = cor[bt];
  xe[k] = X[t_ * 128 + (k & 127)] * emb2[c_ * 256 + k];
  __syncthreads();
  float z = 0.f;
#pragma unroll 8
  for (int d = 0; d < 256; ++d)
    z = fmaf(xe[d], Wk[d * 256 + k], z);
  ZX[bt * 256 + k] = z;
}

// ---------------------------------------------------------------------------
// Fused LSTM (blocks 0,1) + XWT (blocks 2..) kernel — unchanged from round 4.
// ---------------------------------------------------------------------------
__global__ __launch_bounds__(256) void lstm_xwt_kernel(
    const float* __restrict__ ZX, const float* __restrict__ Wr,
    const float* __restrict__ bl, const float* __restrict__ W1,
    const float* __restrict__ X, const float* __restrict__ b1,
    float* __restrict__ G, float* __restrict__ XWT) {
  const int blk = blockIdx.x;
  const int k   = threadIdx.x;

  if (blk >= B_) {
    // ---------------- XWT role ----------------
    __shared__ float xrow[4][128];
    const int sub = k >> 6, lane = k & 63;
    const int p = (blk - B_) * 4 + sub;
    if (p < P_) {
      xrow[sub][lane]      = X[p * 128 + lane];
      xrow[sub][64 + lane] = X[p * 128 + 64 + lane];
    }
    __syncthreads();
    if (p < P_ && lane < 50) {
      float acc = b1[lane];
#pragma unroll 16
      for (int u = 0; u < 128; ++u)
        acc = fmaf(xrow[sub][u], W1[(64 + u) * 50 + lane], acc);
      XWT[lane * P_ + p] = acc;
    }
    return;
  }

  // ---------------- LSTM role ----------------
  const int b   = blk;
  const int g   = k & 3;
  const int u   = k >> 2;
  const int col = g * 64 + u;
  __shared__ __align__(16) float H_s[T_ + 1][64];   // H_s[t] = h(t-1)
  __shared__ __align__(16) float W1_s[64 * 50];

  v2f w2[32];
#pragma unroll
  for (int i = 0; i < 32; ++i) {
    v2f t; t.x = Wr[(2 * i) * 256 + col]; t.y = Wr[(2 * i + 1) * 256 + col];
    w2[i] = t;
  }
  const float blv = bl[col];
  float znext = ZX[(b * T_) * 256 + col];
  for (int i = k; i < 64 * 50; i += 256) W1_s[i] = W1[i];
  if (k < 64) H_s[0][k] = 0.f;
  float c = 0.f;
  __syncthreads();

  for (int t = 0; t < T_; ++t) {
    const float zcur = znext;
    if (t + 1 < T_) znext = ZX[(b * T_ + t + 1) * 256 + col];
    const float4* h4 = (const float4*)&H_s[t][0];
    v2f a0 = {0.f, 0.f}, a1 = {0.f, 0.f}, a2 = {0.f, 0.f}, a3 = {0.f, 0.f};
#pragma unroll
    for (int q = 0; q < 16; ++q) {
      const float4 hq = h4[q];
      v2f hlo; hlo.x = hq.x; hlo.y = hq.y;
      v2f hhi; hhi.x = hq.z; hhi.y = hq.w;
      if (q & 1) {
        a2 = __builtin_elementwise_fma(hlo, w2[2 * q], a2);
        a3 = __builtin_elementwise_fma(hhi, w2[2 * q + 1], a3);
      } else {
        a0 = __builtin_elementwise_fma(hlo, w2[2 * q], a0);
        a1 = __builtin_elementwise_fma(hhi, w2[2 * q + 1], a1);
      }
    }
    const v2f as = (a0 + a2) + (a1 + a3);
    const float z = as.x + as.y + zcur + blv;
    const bool isg2 = (g == 2);
    const float arg = isg2 ? (2.f * z) : (-z);
    const float e   = __expf(arg);
    const float v   = __fdividef(1.f, 1.f + e);
    const float res = isg2 ? fmaf(-2.f, v, 1.f) : v;
    const float v1 = QPERM(res, 177);
    const float v2 = QPERM(res, 78);
    const float v3 = QPERM(res, 27);
    const float ig = (g == 0) ? res : (g == 1) ? v1 : (g == 2) ? v2 : v3;
    const float fg = (g == 1) ? res : (g == 0) ? v1 : (g == 3) ? v2 : v3;
    const float gg = (g == 2) ? res : (g == 3) ? v1 : (g == 0) ? v2 : v3;
    const float og = (g == 3) ? res : (g == 2) ? v1 : (g == 1) ? v2 : v3;
    c = fmaf(fg, c, ig * gg);
    const float th = fmaf(-2.f, __fdividef(1.f, 1.f + __expf(2.f * c)), 1.f);
    if (g == 0) H_s[t + 1][u] = og * th;
    __syncthreads();
  }

  // Epilogue (off serial path): G[b,t,:] = H(t)·W1.
  const v2f* W1_2 = (const v2f*)W1_s;
  v2f*       G_2  = (v2f*)G;
  for (int task = k; task < T_ * 25; task += 256) {
    const int t  = task / 25;
    const int jp = task % 25;
    const float* hrow = &H_s[t + 1][0];
    v2f acc = {0.f, 0.f};
#pragma unroll
    for (int u2 = 0; u2 < 64; ++u2) {
      v2f hb; hb.x = hrow[u2]; hb.y = hrow[u2];
      acc = __builtin_elementwise_fma(hb, W1_2[u2 * 25 + jp], acc);
    }
    G_2[b * (T_ * 25) + task] = acc;
  }
}

// ---------------------------------------------------------------------------
// Main fused kernel v5: thread per (b,p). ALL 50 cosX gather loads are issued
// up front into statically-indexed registers (s-loop fully unrolled), so the
// per-step serial chain no longer contains a dependent global load.
// ---------------------------------------------------------------------------
__global__ __launch_bounds__(256) void out_kernel(
    const int* __restrict__ tgt, const float* __restrict__ cosX,
    const float* __restrict__ G, const float* __restrict__ XWT,
    const float* __restrict__ W2, const float* __restrict__ b2,
    float* __restrict__ out) {
  const int b   = blockIdx.y;
  const int tid = threadIdx.x;
  const int p   = blockIdx.x * 256 + tid;
  __shared__ __align__(16) float G_s[T_ * 50];
  __shared__ __align__(16) float W2_s[50];
  __shared__ int tgt_s[T_];
  for (int i = tid; i < T_ * 50; i += 256) G_s[i] = G[b * T_ * 50 + i];
  if (tid < 50) {
    W2_s[tid]  = W2[tid];
    tgt_s[tid] = tgt[b * T_ + tid];
  }
  __syncthreads();
  if (p >= P_) return;

  // All 50 independent gather loads in flight together (statically indexed
  // -> registers, no scratch).
  float av[T_];
#pragma unroll
  for (int s = 0; s < T_; ++s) av[s] = cosX[tgt_s[s] * P_ + p];

  v2f S2[25];
#pragma unroll
  for (int jj = 0; jj < 25; ++jj) {
    v2f t; t.x = XWT[(2 * jj) * P_ + p]; t.y = XWT[(2 * jj + 1) * P_ + p];
    S2[jj] = t;
  }
  const v2f* W2_2 = (const v2f*)W2_s;
  const float b2v = b2[0];
  const v2f zero2 = {0.f, 0.f};
#pragma unroll
  for (int s = T_ - 1; s >= 0; --s) {
    const v2f* G2 = (const v2f*)&G_s[s * 50];
    v2f av2; av2.x = av[s]; av2.y = av[s];
    v2f acc2; acc2.x = b2v; acc2.y = 0.f;
#pragma unroll
    for (int jj = 0; jj < 25; ++jj) {
      S2[jj] = __builtin_elementwise_fma(av2, G2[jj], S2[jj]);
      const v2f r = __builtin_elementwise_max(S2[jj], zero2);
      acc2 = __builtin_elementwise_fma(r, W2_2[jj], acc2);
    }
    out[(b * T_ + s) * P_ + p] = acc2.x + acc2.y;
  }
}

extern "C" void kernel_launch(void* const* d_in, const int* in_sizes, int n_in,
                              void* d_out, int out_size, void* d_ws, size_t ws_size,
                              hipStream_t stream) {
  const int*   tgt  = (const int*)d_in[0];
  const int*   cor  = (const int*)d_in[1];
  const float* X    = (const float*)d_in[3];
  const float* cosX = (const float*)d_in[4];
  const float* emb2 = (const float*)d_in[6];
  const float* Wk   = (const float*)d_in[7];
  const float* Wr   = (const float*)d_in[8];
  const float* bl   = (const float*)d_in[9];
  const float* W1   = (const float*)d_in[10];
  const float* b1   = (const float*)d_in[11];
  const float* W2   = (const float*)d_in[12];
  const float* b2   = (const float*)d_in[13];
  float* out = (float*)d_out;

  float* ws  = (float*)d_ws;
  float* ZX  = ws;           // 100*256 = 25600 floats
  float* G   = ws + 25600;   // 100*50  =  5000 floats
  float* XWT = ws + 30600;   // 50*5111 = 255550 floats

  const int xw_blocks = (P_ + 3) / 4;  // 1278
  zx_kernel<<<dim3(B_ * T_), dim3(256), 0, stream>>>(tgt, cor, X, emb2, Wk, ZX);
  lstm_xwt_kernel<<<dim3(B_ + xw_blocks), dim3(256), 0, stream>>>(
      ZX, Wr, bl, W1, X, b1, G, XWT);
  out_kernel<<<dim3((P_ + 255) / 256, B_), dim3(256), 0, stream>>>(
      tgt, cosX, G, XWT, W2, b2, out);
}